// Round 7
// baseline (276.247 us; speedup 1.0000x reference)
//
#include <hip/hip_runtime.h>
#include <hip/hip_bf16.h>
#include <cstdint>
#include <cstddef>

// MyBaseRNN: out[t,b,h] = tanh( x[t,b,:]·W[h,:] + ib[h] + h0[b,:]·U[h,:] + hb[h] )
// hidden = out[T-1].  GEMM: M=131072, N=512, K=512.
// R7: counted-vmcnt ring-3 pipeline (T3+T4). BK=32, 3 x 24KB LDS bufs
// (72KB -> 2 blocks/CU). Per step: vmcnt(6) [stage t done, t+1 in flight]
// -> raw s_barrier (no vmcnt(0) drain!) -> issue stage(t+2) -> compute(t).
// Loads never drain; ring-3 + 1 barrier/step is overwrite-safe (buf (t+2)%3
// last read in step t-1, sealed by this step's barrier).
// compute/stage/swizzles lifted verbatim from R6 (correctness-proven).

#define T_LEN 2048
#define BATCH 64
#define ISZ 512
#define HSZ 512
#define MTOT (T_LEN * BATCH) /* 131072 */

#define BM 128
#define BN 128
#define NMT (MTOT / BM) /* 1024 m-tiles */

typedef __attribute__((ext_vector_type(8))) __bf16 bf16x8;
typedef __attribute__((ext_vector_type(4))) __bf16 bf16x4;
typedef __attribute__((ext_vector_type(4))) float f32x4;

#define GLOBAL_AS __attribute__((address_space(1)))
#define LDS_AS __attribute__((address_space(3)))

__device__ __forceinline__ float fast_tanh(float v) {
    float e = __expf(2.0f * v);
    return 1.0f - 2.0f / (e + 1.0f);
}

// ---------- Kernel 1: fused W->bf16 convert (blocks 0..127) + uh (blocks 128..191) ----
__global__ __launch_bounds__(512) void prep_kernel(const float* __restrict__ W,
                                                   __bf16* __restrict__ Wbf,
                                                   const float* __restrict__ prev,
                                                   const float* __restrict__ U,
                                                   const float* __restrict__ hb,
                                                   const float* __restrict__ ib,
                                                   float* __restrict__ uh) {
    if (blockIdx.x < 128) {
        int i = blockIdx.x * 512 + threadIdx.x; // 65536 f32x4 total
        f32x4 f = ((const f32x4*)W)[i];
        bf16x4 v;
        v[0] = (__bf16)f[0]; v[1] = (__bf16)f[1];
        v[2] = (__bf16)f[2]; v[3] = (__bf16)f[3];
        ((bf16x4*)Wbf)[i] = v;
    } else {
        __shared__ float sp[HSZ];
        int b = blockIdx.x - 128, h = threadIdx.x;
        sp[h] = prev[b * HSZ + h];
        __syncthreads();
        const float* urow = U + (size_t)h * HSZ;
        float acc = 0.f;
#pragma unroll 4
        for (int i = 0; i < HSZ; i += 4) {
            f32x4 u4 = *(const f32x4*)(urow + i);
            acc += u4[0] * sp[i] + u4[1] * sp[i + 1] + u4[2] * sp[i + 2] + u4[3] * sp[i + 3];
        }
        uh[b * HSZ + h] = acc + hb[h] + ib[h];
    }
}

// ---------- Kernel 2: pipelined GEMM + bias + tanh (+ fused hidden copy) ----------
// 4096 blocks x 256 threads (4 waves, 2x2). Per buf: A fp32 [128][32]
// (16KB, 128B rows, slot s at s^(r&7)) at 0; B bf16 [128][32] (8KB, 64B
// rows, slot s at s^((r>>1)&3)) at 16384.
__global__ __launch_bounds__(256) void gemm_tanh_kernel(
        const float* __restrict__ x, const __bf16* __restrict__ Wbf,
        const float* __restrict__ uh, float* __restrict__ out,
        float* __restrict__ hid) {
    __shared__ __attribute__((aligned(16))) char lds[3][24576]; // 72 KB ring

    // XCD-bijective swizzle: nwg=4096, cpx=512; 4 n-tiles of an m-panel
    // consecutive on one XCD.
    int orig = blockIdx.x;
    int wg = (orig & 7) * 512 + (orig >> 3);
    int mt = wg >> 2, nt = wg & 3;

    int tid = threadIdx.x;
    int lane = tid & 63, wid = tid >> 6;
    int wr = wid >> 1, wc = wid & 1;
    int l15 = lane & 15, l4 = lane >> 4;

    const size_t m0 = (size_t)mt * BM;
    const int n0 = nt * BN;

    // --- stage address precompute (pre-swizzled global src, linear LDS dst) ---
    // A chunk = 1KB = 8 rows x 8 slots(16B); lane: row l>>3, dest slot l&7,
    // source slot (l&7)^(l>>3).
    int a_r = lane >> 3, a_s = lane & 7;
    const float* aSrc[4];
#pragma unroll
    for (int j = 0; j < 4; ++j) {
        int c = wid * 4 + j; // 16 chunks cover 128 rows
        aSrc[j] = x + (m0 + c * 8 + a_r) * ISZ + ((a_s ^ a_r) << 2);
    }
    // B chunk = 1KB = 16 rows x 4 slots(16B); lane: row l>>2, dest slot l&3,
    // source slot (l&3)^((l>>3)&3).
    int b_r = lane >> 2, b_s = lane & 3, b_x = (lane >> 3) & 3;
    const __bf16* bSrc[2];
#pragma unroll
    for (int j = 0; j < 2; ++j) {
        int c = wid * 2 + j; // 8 chunks cover 128 rows
        bSrc[j] = Wbf + (size_t)(n0 + c * 16 + b_r) * ISZ + ((b_s ^ b_x) << 3);
    }

    auto stage = [&](char* base, int t) {
        int ks = t * 32;
#pragma unroll
        for (int j = 0; j < 4; ++j)
            __builtin_amdgcn_global_load_lds(
                (const GLOBAL_AS uint32_t*)(aSrc[j] + ks),
                (LDS_AS uint32_t*)(base + (wid * 4 + j) * 1024), 16, 0, 0);
#pragma unroll
        for (int j = 0; j < 2; ++j)
            __builtin_amdgcn_global_load_lds(
                (const GLOBAL_AS uint32_t*)(bSrc[j] + ks),
                (LDS_AS uint32_t*)(base + 16384 + (wid * 2 + j) * 1024), 16, 0, 0);
    };

    f32x4 acc[4][4] = {};

    auto compute = [&](const char* base) {
        bf16x8 bfr[4];
#pragma unroll
        for (int ni = 0; ni < 4; ++ni) {
            int row = wc * 64 + ni * 16 + l15;
            bfr[ni] = *(const bf16x8*)(base + 16384 + row * 64 +
                                       ((l4 * 16) ^ (((row >> 1) & 3) << 4)));
        }
#pragma unroll
        for (int mi = 0; mi < 4; ++mi) {
            int row = wr * 64 + mi * 16 + l15;
            int xo = (row & 7) << 4;
            f32x4 a0 = *(const f32x4*)(base + row * 128 + ((l4 * 32) ^ xo));
            f32x4 a1 = *(const f32x4*)(base + row * 128 + ((l4 * 32 + 16) ^ xo));
            bf16x8 av;
            av[0] = (__bf16)a0[0]; av[1] = (__bf16)a0[1];
            av[2] = (__bf16)a0[2]; av[3] = (__bf16)a0[3];
            av[4] = (__bf16)a1[0]; av[5] = (__bf16)a1[1];
            av[6] = (__bf16)a1[2]; av[7] = (__bf16)a1[3];
#pragma unroll
            for (int ni = 0; ni < 4; ++ni)
                acc[mi][ni] = __builtin_amdgcn_mfma_f32_16x16x32_bf16(
                    bfr[ni], av, acc[mi][ni], 0, 0, 0);
        }
    };

    // prologue: two stages in flight (12 loads)
    stage(lds[0], 0);
    stage(lds[1], 1);

#pragma unroll 1
    for (int t = 0; t < 15; ++t) {
        // wait for stage(t) only; stage(t+1)'s 6 loads stay in flight
        asm volatile("s_waitcnt vmcnt(6)" ::: "memory");
        __builtin_amdgcn_sched_barrier(0);
        __builtin_amdgcn_s_barrier(); // raw: no vmcnt(0) drain
        __builtin_amdgcn_sched_barrier(0);
        int nxt = t + 2;
        if (nxt < 16) stage(lds[nxt % 3], nxt); // issue after barrier (safe)
        compute(lds[t % 3]);
    }
    // final step t=15
    asm volatile("s_waitcnt vmcnt(0)" ::: "memory");
    __builtin_amdgcn_sched_barrier(0);
    __builtin_amdgcn_s_barrier();
    __builtin_amdgcn_sched_barrier(0);
    compute(lds[0]); // 15 % 3 == 0

    // ---- epilogue: + uh, tanh, dwordx4 stores. Swapped-operand D layout:
    // col (lane&15) = m-local, row ((lane>>4)*4+r) = n-local.
    bool lastTile = (mt == NMT - 1);
#pragma unroll
    for (int mi = 0; mi < 4; ++mi) {
        int ml = wr * 64 + mi * 16 + l15;
        size_t m = m0 + ml;
        int bb = ml & 63; // batch index (m0 multiple of 128)
#pragma unroll
        for (int ni = 0; ni < 4; ++ni) {
            int nb = n0 + wc * 64 + ni * 16 + l4 * 4;
            f32x4 u4 = *(const f32x4*)&uh[bb * HSZ + nb];
            f32x4 v;
#pragma unroll
            for (int r = 0; r < 4; ++r) v[r] = fast_tanh(acc[mi][ni][r] + u4[r]);
            *(f32x4*)&out[m * HSZ + nb] = v;
            if (lastTile && ml >= BM - BATCH)
                *(f32x4*)&hid[(size_t)(ml - (BM - BATCH)) * HSZ + nb] = v;
        }
    }
}

extern "C" void kernel_launch(void* const* d_in, const int* in_sizes, int n_in,
                              void* d_out, int out_size, void* d_ws, size_t ws_size,
                              hipStream_t stream) {
    const float* x  = (const float*)d_in[0];
    const float* ph = (const float*)d_in[1];
    const float* W  = (const float*)d_in[2];
    const float* U  = (const float*)d_in[3];
    const float* hb = (const float*)d_in[4];
    const float* ib = (const float*)d_in[5];
    float* out = (float*)d_out;
    float* hid = out + (size_t)MTOT * HSZ;

    __bf16* Wbf = (__bf16*)d_ws;                      // 512 KB
    float* uh   = (float*)((char*)d_ws + 512 * 1024); // 128 KB

    hipLaunchKernelGGL(prep_kernel, dim3(192), dim3(512), 0, stream,
                       W, Wbf, ph, U, hb, ib, uh);
    hipLaunchKernelGGL(gemm_tanh_kernel, dim3(4096), dim3(256), 0, stream,
                       x, Wbf, uh, out, hid);
}

// Round 8
// 235.721 us; speedup vs baseline: 1.1719x; 1.1719x over previous
//
#include <hip/hip_runtime.h>
#include <hip/hip_bf16.h>
#include <cstdint>
#include <cstddef>

// MyBaseRNN: out[t,b,h] = tanh( x[t,b,:]·W[h,:] + ib[h] + h0[b,:]·U[h,:] + hb[h] )
// hidden = out[T-1].  GEMM: M=131072, N=512, K=512.
// R8: occupancy attack. Evidence R1-R7: dur tracks occupancy monotonically
// (42%->212us, 32%->241, 22%->268); acc=64 AGPR + 64 arch = 128 regs capped
// us at 4 waves/SIMD. Halve the wave tile: 64x128 block, 4 waves of 32x64
// (acc[2][4] = 32 AGPR, target total ~96 -> 5 waves/SIMD ~62% occ), 24KB LDS
// (~5 blocks/CU). Phase structure, swizzles, epilogue = R4 verbatim
// (proven). B re-read 2x is L2-absorbed (W = 512KB << 4MB/XCD).

#define T_LEN 2048
#define BATCH 64
#define ISZ 512
#define HSZ 512
#define MTOT (T_LEN * BATCH) /* 131072 */

#define BM 64
#define BN 128
#define BK 64
#define NMT (MTOT / BM) /* 2048 m-tiles */

typedef __attribute__((ext_vector_type(8))) __bf16 bf16x8;
typedef __attribute__((ext_vector_type(4))) __bf16 bf16x4;
typedef __attribute__((ext_vector_type(4))) float f32x4;

#define GLOBAL_AS __attribute__((address_space(1)))
#define LDS_AS __attribute__((address_space(3)))

__device__ __forceinline__ float fast_tanh(float v) {
    float e = __expf(2.0f * v);
    return 1.0f - 2.0f / (e + 1.0f);
}

// ---------- Kernel 1: fused W->bf16 convert (blocks 0..127) + uh (blocks 128..191) ----
__global__ __launch_bounds__(512) void prep_kernel(const float* __restrict__ W,
                                                   __bf16* __restrict__ Wbf,
                                                   const float* __restrict__ prev,
                                                   const float* __restrict__ U,
                                                   const float* __restrict__ hb,
                                                   const float* __restrict__ ib,
                                                   float* __restrict__ uh) {
    if (blockIdx.x < 128) {
        int i = blockIdx.x * 512 + threadIdx.x; // 65536 f32x4 total
        f32x4 f = ((const f32x4*)W)[i];
        bf16x4 v;
        v[0] = (__bf16)f[0]; v[1] = (__bf16)f[1];
        v[2] = (__bf16)f[2]; v[3] = (__bf16)f[3];
        ((bf16x4*)Wbf)[i] = v;
    } else {
        __shared__ float sp[HSZ];
        int b = blockIdx.x - 128, h = threadIdx.x;
        sp[h] = prev[b * HSZ + h];
        __syncthreads();
        const float* urow = U + (size_t)h * HSZ;
        float acc = 0.f;
#pragma unroll 4
        for (int i = 0; i < HSZ; i += 4) {
            f32x4 u4 = *(const f32x4*)(urow + i);
            acc += u4[0] * sp[i] + u4[1] * sp[i + 1] + u4[2] * sp[i + 2] + u4[3] * sp[i + 3];
        }
        uh[b * HSZ + h] = acc + hb[h] + ib[h];
    }
}

// ---------- Kernel 2: GEMM + bias + tanh (+ fused hidden copy) ----------
// 8192 blocks x 256 threads (4 waves: 2m x 2n, each 32x64 output).
// acc[2][4] f32x4 = 32 AGPR. Single-buffered 24 KB LDS, XOR swizzle
// (byte col ^= (row&7)<<4), R4-proven conflict-free.
__global__ __launch_bounds__(256, 5) void gemm_tanh_kernel(
        const float* __restrict__ x, const __bf16* __restrict__ Wbf,
        const float* __restrict__ uh, float* __restrict__ out,
        float* __restrict__ hid) {
    __shared__ __attribute__((aligned(16))) __bf16 sA[BM * BK]; //  8 KB
    __shared__ __attribute__((aligned(16))) __bf16 sB[BN * BK]; // 16 KB

    // XCD-bijective swizzle: nwg=8192 (%8==0), cpx=1024. 4 consecutive
    // locals = same m-panel's 4 n-tiles -> A-panel shared in one XCD's L2.
    int orig = blockIdx.x;
    int wg = (orig & 7) * 1024 + (orig >> 3);
    int mt = wg >> 2, nt = wg & 3;

    int tid = threadIdx.x;
    int lane = tid & 63, wid = tid >> 6;
    int wr = wid >> 1, wc = wid & 1;
    int l15 = lane & 15, l4 = lane >> 4;

    const size_t m0 = (size_t)mt * BM;
    const int n0 = nt * BN;

    f32x4 acc[2][4] = {};

#pragma unroll 1
    for (int t = 0; t < 8; ++t) {
        int ks = t * BK;
        // ---- stage B first: async global_load_lds, pre-swizzled source ----
#pragma unroll
        for (int j = 0; j < 4; ++j) {
            int chunk = wid * 4 + j;                  // 0..15 (1KB each)
            int row = chunk * 8 + (lane >> 3);        // dest row (linear)
            int cb = ((lane & 7) ^ (lane >> 3)) << 4; // swizzled source col-byte
            const __bf16* g = Wbf + (size_t)(n0 + row) * ISZ + ks + (cb >> 1);
            __builtin_amdgcn_global_load_lds((const GLOBAL_AS uint32_t*)g,
                (LDS_AS uint32_t*)((char*)sB + chunk * 1024), 16, 0, 0);
        }
        // ---- stage A: fp32 load -> cvt -> swizzled LDS write (transient) ----
#pragma unroll
        for (int it = 0; it < 2; ++it) {
            int p = it * 256 + tid;        // 512 pairs: 64 rows x 8 pairs
            int row = p >> 3, pc = p & 7;
            const float* src = x + (m0 + row) * ISZ + ks + pc * 8;
            f32x4 f0 = *(const f32x4*)src;
            f32x4 f1 = *(const f32x4*)(src + 4);
            bf16x8 v;
            v[0] = (__bf16)f0[0]; v[1] = (__bf16)f0[1];
            v[2] = (__bf16)f0[2]; v[3] = (__bf16)f0[3];
            v[4] = (__bf16)f1[0]; v[5] = (__bf16)f1[1];
            v[6] = (__bf16)f1[2]; v[7] = (__bf16)f1[3];
            int cb = (pc * 16) ^ ((row & 7) << 4);
            *(bf16x8*)((char*)sA + row * 128 + cb) = v;
        }
        __syncthreads();
        // ---- compute: 2 k-chunks, swizzled ds_read + 8 MFMA each ----
#pragma unroll
        for (int kk = 0; kk < 2; ++kk) {
            bf16x8 af[2], bfr[4];
#pragma unroll
            for (int mi = 0; mi < 2; ++mi) {
                int row = wr * 32 + mi * 16 + l15;
                int cb = (kk * 64 + l4 * 16) ^ ((row & 7) << 4);
                af[mi] = *(const bf16x8*)((const char*)sA + row * 128 + cb);
            }
#pragma unroll
            for (int ni = 0; ni < 4; ++ni) {
                int row = wc * 64 + ni * 16 + l15;
                int cb = (kk * 64 + l4 * 16) ^ ((row & 7) << 4);
                bfr[ni] = *(const bf16x8*)((const char*)sB + row * 128 + cb);
            }
#pragma unroll
            for (int mi = 0; mi < 2; ++mi)
#pragma unroll
                for (int ni = 0; ni < 4; ++ni)
                    acc[mi][ni] = __builtin_amdgcn_mfma_f32_16x16x32_bf16(
                        bfr[ni], af[mi], acc[mi][ni], 0, 0, 0);
        }
        if (t < 7) __syncthreads();
    }

    // ---- epilogue: + uh, tanh, dwordx4 stores. Swapped-operand D layout:
    // col (lane&15) = m-local, row ((lane>>4)*4+r) = n-local.
    // BM==BATCH==64: batch index b == ml; last m-tile is exactly t=T-1.
    bool lastTile = (mt == NMT - 1);
#pragma unroll
    for (int mi = 0; mi < 2; ++mi) {
        int ml = wr * 32 + mi * 16 + l15;
        size_t m = m0 + ml;
#pragma unroll
        for (int ni = 0; ni < 4; ++ni) {
            int nb = n0 + wc * 64 + ni * 16 + l4 * 4;
            f32x4 u4 = *(const f32x4*)&uh[ml * HSZ + nb];
            f32x4 v;
#pragma unroll
            for (int r = 0; r < 4; ++r) v[r] = fast_tanh(acc[mi][ni][r] + u4[r]);
            *(f32x4*)&out[m * HSZ + nb] = v;
            if (lastTile)
                *(f32x4*)&hid[(size_t)ml * HSZ + nb] = v;
        }
    }
}

extern "C" void kernel_launch(void* const* d_in, const int* in_sizes, int n_in,
                              void* d_out, int out_size, void* d_ws, size_t ws_size,
                              hipStream_t stream) {
    const float* x  = (const float*)d_in[0];
    const float* ph = (const float*)d_in[1];
    const float* W  = (const float*)d_in[2];
    const float* U  = (const float*)d_in[3];
    const float* hb = (const float*)d_in[4];
    const float* ib = (const float*)d_in[5];
    float* out = (float*)d_out;
    float* hid = out + (size_t)MTOT * HSZ;

    __bf16* Wbf = (__bf16*)d_ws;                      // 512 KB
    float* uh   = (float*)((char*)d_ws + 512 * 1024); // 128 KB

    hipLaunchKernelGGL(prep_kernel, dim3(192), dim3(512), 0, stream,
                       W, Wbf, ph, U, hb, ib, uh);
    hipLaunchKernelGGL(gemm_tanh_kernel, dim3(MTOT / BM * (HSZ / BN)), dim3(256),
                       0, stream, x, Wbf, uh, out, hid);
}